// Round 2
// baseline (535.731 us; speedup 1.0000x reference)
//
#include <hip/hip_runtime.h>
#include <math.h>

#define Bz   8
#define Lz   8192
#define Hz   1024
#define Nz   64
#define BLz  (Bz * Lz)   // 65536

typedef __attribute__((ext_vector_type(8))) short bf16x8;
typedef __attribute__((ext_vector_type(4))) float f32x4;

__device__ inline unsigned int bfpack2(float a, float b) {
    // round-to-nearest-ish (round half up) bf16 pack of two floats
    unsigned int ua = __float_as_uint(a) + 0x8000u;
    unsigned int ub = __float_as_uint(b) + 0x8000u;
    return (ua >> 16) | (ub & 0xFFFF0000u);
}
__device__ inline unsigned short bf1(float a) {
    return (unsigned short)((__float_as_uint(a) + 0x8000u) >> 16);
}
__device__ inline bf16x8 packa(float4 v0, float4 v1) {
    union { uint4 u; bf16x8 h; } cv;
    cv.u.x = bfpack2(v0.x, v0.y);
    cv.u.y = bfpack2(v0.z, v0.w);
    cv.u.z = bfpack2(v1.x, v1.y);
    cv.u.w = bfpack2(v1.z, v1.w);
    return cv.h;
}

// ---------------------------------------------------------------------------
// Prep: WinT[n][k] = bf16(Win[k][n])  (64 x 1024)
//       WoutT[h][n] = bf16(Wout[n][h]) (1024 x 64)
// ---------------------------------------------------------------------------
__global__ __launch_bounds__(256) void prep_kernel(
    const float* __restrict__ Win, const float* __restrict__ Wout,
    unsigned short* __restrict__ WinT, unsigned short* __restrict__ WoutT)
{
    int i = blockIdx.x * 256 + threadIdx.x;   // 0 .. 131071
    if (i < 65536) {
        int n = i >> 10, k = i & 1023;
        WinT[i] = bf1(Win[k * Nz + n]);
    } else {
        int j = i - 65536;
        int h = j >> 6, n = j & 63;
        WoutT[j] = bf1(Wout[n * Hz + h]);
    }
}

// ---------------------------------------------------------------------------
// GEMM1 v2: u[bl,n] = input[bl,:] * Win[:,n]  (M=65536, N=64, K=1024)
// BARRIER-FREE / LDS-FREE. One wave per block, 32 rows per wave.
// A fragments loaded directly from global fp32 (16-row x 128B segments,
// full-line coalescing) and packed to bf16 in-register. B (WinT) is 128 KB,
// L1/L2-resident; each wave loads its own B frags (8 KB per kc) from cache.
// Ping-pong 2-buffer register prefetch: consume buf0 while buf1 in flight.
// No __syncthreads -> no vmcnt(0) drain -> loads stream continuously.
// Writes u TRANSPOSED: ut[(b*Nz+n)*Lz + l] for the scan.
// ---------------------------------------------------------------------------
#define LOADKC(AB, BB, OFF)                                                  \
    if ((OFF) < Hz) {                                                        \
        const float* ap0_ = a0p + (OFF);                                     \
        const float* ap1_ = a1p + (OFF);                                     \
        AB[0] = *reinterpret_cast<const float4*>(ap0_);                      \
        AB[1] = *reinterpret_cast<const float4*>(ap0_ + 4);                  \
        AB[2] = *reinterpret_cast<const float4*>(ap0_ + 32);                 \
        AB[3] = *reinterpret_cast<const float4*>(ap0_ + 36);                 \
        AB[4] = *reinterpret_cast<const float4*>(ap1_);                      \
        AB[5] = *reinterpret_cast<const float4*>(ap1_ + 4);                  \
        AB[6] = *reinterpret_cast<const float4*>(ap1_ + 32);                 \
        AB[7] = *reinterpret_cast<const float4*>(ap1_ + 36);                 \
        BB[0] = *reinterpret_cast<const bf16x8*>(b0p + (OFF));               \
        BB[1] = *reinterpret_cast<const bf16x8*>(b0p + (OFF) + 32);          \
        BB[2] = *reinterpret_cast<const bf16x8*>(b1p + (OFF));               \
        BB[3] = *reinterpret_cast<const bf16x8*>(b1p + (OFF) + 32);          \
        BB[4] = *reinterpret_cast<const bf16x8*>(b2p + (OFF));               \
        BB[5] = *reinterpret_cast<const bf16x8*>(b2p + (OFF) + 32);          \
        BB[6] = *reinterpret_cast<const bf16x8*>(b3p + (OFF));               \
        BB[7] = *reinterpret_cast<const bf16x8*>(b3p + (OFF) + 32);          \
    }

#define CONSKC(AB, BB)                                                       \
    {                                                                        \
        bf16x8 a00 = packa(AB[0], AB[1]);                                    \
        bf16x8 a01 = packa(AB[2], AB[3]);                                    \
        bf16x8 a10 = packa(AB[4], AB[5]);                                    \
        bf16x8 a11 = packa(AB[6], AB[7]);                                    \
        _Pragma("unroll")                                                    \
        for (int nt = 0; nt < 4; ++nt) {                                     \
            acc[0][nt] = __builtin_amdgcn_mfma_f32_16x16x32_bf16(            \
                a00, BB[nt * 2 + 0], acc[0][nt], 0, 0, 0);                   \
            acc[0][nt] = __builtin_amdgcn_mfma_f32_16x16x32_bf16(            \
                a01, BB[nt * 2 + 1], acc[0][nt], 0, 0, 0);                   \
            acc[1][nt] = __builtin_amdgcn_mfma_f32_16x16x32_bf16(            \
                a10, BB[nt * 2 + 0], acc[1][nt], 0, 0, 0);                   \
            acc[1][nt] = __builtin_amdgcn_mfma_f32_16x16x32_bf16(            \
                a11, BB[nt * 2 + 1], acc[1][nt], 0, 0, 0);                   \
        }                                                                    \
    }

__global__ __launch_bounds__(64) void gemm_in_kernel(
    const float* __restrict__ inp, const unsigned short* __restrict__ WinT,
    float* __restrict__ u)
{
    const int lane = threadIdx.x;
    const int nl   = lane & 15;
    const int q    = lane >> 4;
    const size_t rowBase = (size_t)blockIdx.x * 32;

    const float* a0p = inp + (rowBase + nl) * Hz + q * 8;
    const float* a1p = inp + (rowBase + 16 + nl) * Hz + q * 8;
    const unsigned short* b0p = WinT + (size_t)(0 * 16 + nl) * Hz + q * 8;
    const unsigned short* b1p = WinT + (size_t)(1 * 16 + nl) * Hz + q * 8;
    const unsigned short* b2p = WinT + (size_t)(2 * 16 + nl) * Hz + q * 8;
    const unsigned short* b3p = WinT + (size_t)(3 * 16 + nl) * Hz + q * 8;

    f32x4 acc[2][4];
#pragma unroll
    for (int m = 0; m < 2; ++m)
#pragma unroll
        for (int nt = 0; nt < 4; ++nt) acc[m][nt] = (f32x4){0.f, 0.f, 0.f, 0.f};

    float4 A0[8], A1[8];
    bf16x8 B0[8], B1[8];
    LOADKC(A0, B0, 0)
    LOADKC(A1, B1, 64)

#pragma unroll
    for (int g = 0; g < 8; ++g) {
        CONSKC(A0, B0)
        LOADKC(A0, B0, g * 128 + 128)
        CONSKC(A1, B1)
        LOADKC(A1, B1, g * 128 + 192)
    }

    // epilogue: C/D col = lane&15 (n), row = q*4+reg (l). Transposed write:
    // ut[(b*Nz+n)*Lz + l] as one f32x4 per (m,nt). 8192 % 32 == 0 so a
    // 32-row block never straddles a batch boundary.
    const int bI = (int)(rowBase >> 13);
    const int l0 = ((int)rowBase & (Lz - 1)) + q * 4;
#pragma unroll
    for (int m = 0; m < 2; ++m)
#pragma unroll
        for (int nt = 0; nt < 4; ++nt) {
            const int nn = nt * 16 + nl;
            *reinterpret_cast<f32x4*>(
                u + (((size_t)(bI * Nz + nn)) << 13) + (l0 + m * 16)) = acc[m][nt];
        }
}

// ---------------------------------------------------------------------------
// Scan: x[t] = a*x[t-1] + u[t] (complex a). conv written as bf16.
// u is TRANSPOSED: ut[(b*Nz+n)*Lz + l] -> thread n streams its own row with
// float4 loads. 64 steps/group, 2-group ping-pong register prefetch.
// ---------------------------------------------------------------------------
#define CHUNK 512
#define WARM  192
#define GSTEP 64

#define SSTEP(UV, IDX)                                              \
    {                                                               \
        float nr_ = fmaf(ar, xr, fmaf(-ai, xi, (UV)));              \
        float ni_ = fmaf(ar, xi, ai * xr);                          \
        xr = nr_; xi = ni_;                                         \
        if (emit_) cp_[(size_t)(IDX) * Nz] = bf1(xr);               \
    }

#define DO_GROUP(BUF, G)                                            \
    {                                                               \
        const int g_ = (G);                                         \
        const bool emit_ = (g_ >= emitG);                           \
        const bool pf_ = (g_ + 2 < nG);                             \
        unsigned short* cp_ = cb + (size_t)(g_ * GSTEP) * Nz;       \
        const float4* np_ = up + (g_ + 2) * (GSTEP / 4);            \
        _Pragma("unroll")                                           \
        for (int k = 0; k < 16; ++k) {                              \
            float4 v_ = BUF[k];                                     \
            if (pf_) BUF[k] = np_[k];                               \
            SSTEP(v_.x, k * 4 + 0)                                  \
            SSTEP(v_.y, k * 4 + 1)                                  \
            SSTEP(v_.z, k * 4 + 2)                                  \
            SSTEP(v_.w, k * 4 + 3)                                  \
        }                                                           \
    }

__global__ __launch_bounds__(64) void scan_kernel(
    const float* __restrict__ ut, const float* __restrict__ init,
    const float* __restrict__ freq, const float* __restrict__ dec,
    unsigned short* __restrict__ convb, float* __restrict__ fs, int fs_mode)
{
    const int n = threadIdx.x;
    const int b = blockIdx.x;
    const int c = blockIdx.y;

    const float mag = expf(-expf(dec[n]));
    const float fr  = freq[n];
    const float ar  = mag * cosf(fr);
    const float ai  = mag * sinf(fr);

    const int s0    = (c == 0) ? 0 : (c * CHUNK - WARM);                 // mult of 16
    const int nG    = (c == 0) ? (CHUNK / GSTEP) : ((CHUNK + WARM) / GSTEP); // 8 or 11
    const int emitG = (c == 0) ? 0 : (WARM / GSTEP);                     // 0 or 3

    const float4* up = reinterpret_cast<const float4*>(
                           ut + (((size_t)(b * Nz + n)) << 13)) + (s0 >> 2);
    unsigned short* cb = convb + ((size_t)b * Lz + s0) * Nz + n;

    float xr = (c == 0) ? init[b * Nz + n] : 0.f;
    float xi = 0.f;

    float4 bufA[16], bufB[16];
#pragma unroll
    for (int k = 0; k < 16; ++k) bufA[k] = up[k];
#pragma unroll
    for (int k = 0; k < 16; ++k) bufB[k] = up[16 + k];

    const int nG2 = nG & ~1;
    for (int g = 0; g < nG2; g += 2) {
        DO_GROUP(bufA, g)
        DO_GROUP(bufB, g + 1)
    }
    if (nG & 1) { DO_GROUP(bufA, nG - 1) }

    if (c == (Lz / CHUNK) - 1 && fs_mode) {
        if (fs_mode == 2) {
            fs[(b * Nz + n) * 2 + 0] = xr;
            fs[(b * Nz + n) * 2 + 1] = xi;
        } else {
            fs[b * Nz + n] = xr;
        }
    }
}

// ---------------------------------------------------------------------------
// GEMM2 v2: out[bl,h] = conv[bl,:] * Wout[:,h]  (M=65536, N=1024, K=64)
// OPERAND-SWAPPED: compute D[h][bl] = WoutT[h][n] . conv^T[n][bl] so that
// D's row axis (q*4+reg) walks h, the contiguous axis of out -> one f32x4
// store per lane per 16x16 tile (was 4 scalar dwords).
// B fragment (conv row, contiguous bf16x8) loaded ONCE per wave, reused
// across all 16 h-tiles. WoutT slice staged in padded LDS.
// block 512 (8 waves): bl-tile 128 (wave: 16 bl), h-slice 256 (16 h-tiles).
// ---------------------------------------------------------------------------
__global__ __launch_bounds__(512) void gemm_out_kernel(
    const unsigned short* __restrict__ convb,
    const unsigned short* __restrict__ WoutT,
    float* __restrict__ out)
{
    __shared__ unsigned short sW[256][72];   // 36.9 KB, pad 72: 2-way alias only

    const int t    = threadIdx.x;
    const int wid  = t >> 6;
    const int lane = t & 63;
    const int nl   = lane & 15;
    const int q    = lane >> 4;
    const int hBase = blockIdx.x * 256;
    const size_t blBase = (size_t)blockIdx.y * 128 + wid * 16;

    // stage WoutT slice: 256 h-rows x 64 n
#pragma unroll
    for (int j = 0; j < 4; ++j) {
        int f = j * 512 + t;
        int r = f >> 3, c = f & 7;
        uint4 v = *reinterpret_cast<const uint4*>(WoutT + (size_t)(hBase + r) * Nz + c * 8);
        *reinterpret_cast<uint4*>(&sW[r][c * 8]) = v;
    }

    // B fragments: B[k=n][col=bl] -> lane nl = bl, k = ks*32 + q*8 + j
    const unsigned short* bp = convb + (blBase + nl) * Nz + q * 8;
    bf16x8 b0 = *reinterpret_cast<const bf16x8*>(bp);        // ks=0
    bf16x8 b1 = *reinterpret_cast<const bf16x8*>(bp + 32);   // ks=1
    __syncthreads();

    float* op = out + (blBase + nl) * Hz + hBase + q * 4;
    const f32x4 zero = (f32x4){0.f, 0.f, 0.f, 0.f};
#pragma unroll
    for (int ht = 0; ht < 16; ++ht) {
        // A fragments: A[row=h_sub][k=n] -> lane nl = h_sub
        bf16x8 w0 = *reinterpret_cast<bf16x8*>(&sW[ht * 16 + nl][q * 8]);
        bf16x8 w1 = *reinterpret_cast<bf16x8*>(&sW[ht * 16 + nl][32 + q * 8]);
        f32x4 acc = __builtin_amdgcn_mfma_f32_16x16x32_bf16(w0, b0, zero, 0, 0, 0);
        acc = __builtin_amdgcn_mfma_f32_16x16x32_bf16(w1, b1, acc, 0, 0, 0);
        // D: row (h) = q*4+reg contiguous in out -> vector store
        *reinterpret_cast<f32x4*>(op + ht * 16) = acc;
    }
}

// ---------------------------------------------------------------------------
extern "C" void kernel_launch(void* const* d_in, const int* in_sizes, int n_in,
                              void* d_out, int out_size, void* d_ws, size_t ws_size,
                              hipStream_t stream)
{
    const float* inp  = (const float*)d_in[0];   // (B, L, H)
    const float* init = (const float*)d_in[1];   // (B, N)
    const float* Win  = (const float*)d_in[2];   // (H, N)
    const float* Wout = (const float*)d_in[3];   // (N, H)
    const float* freq = (const float*)d_in[4];   // (N,)
    const float* dec  = (const float*)d_in[5];   // (N,)
    float* out = (float*)d_out;

    char* ws = (char*)d_ws;
    float*          u     = (float*)ws;                               // 16.78 MB (ut, transposed)
    unsigned short* convb = (unsigned short*)(ws + (size_t)BLz * Nz * 4);       // 8.39 MB
    unsigned short* WinT  = (unsigned short*)(ws + (size_t)BLz * Nz * 6);       // 128 KB
    unsigned short* WoutT = WinT + (size_t)Nz * Hz;                             // 128 KB

    const int extra   = out_size - BLz * Hz;
    const int fs_mode = (extra >= 2 * Bz * Nz) ? 2 : (extra >= Bz * Nz ? 1 : 0);
    float* fs = out + (size_t)BLz * Hz;

    hipLaunchKernelGGL(prep_kernel, dim3(512), dim3(256), 0, stream,
                       Win, Wout, WinT, WoutT);
    hipLaunchKernelGGL(gemm_in_kernel, dim3(BLz / 32), dim3(64), 0, stream,
                       inp, WinT, u);
    hipLaunchKernelGGL(scan_kernel, dim3(Bz, Lz / CHUNK), dim3(64), 0, stream,
                       u, init, freq, dec, convb, fs, fs_mode);
    hipLaunchKernelGGL(gemm_out_kernel, dim3(Hz / 256, BLz / 128), dim3(512), 0, stream,
                       convb, WoutT, out);
}